// Round 1
// baseline (12649.552 us; speedup 1.0000x reference)
//
#include <hip/hip_runtime.h>
#include <math.h>

// Seq2Seq decode-only implementation.
// Key facts exploited:
//  - Encoder output is discarded by the reference; decoder starts from zero
//    state and depends only on tags, l2_* weights, lin_W/b, START=1.
//  - Output layout (float32): probabilities [4096,31,256] flat, then
//    outputs (argmax indices as float) [4096,30] flat.
// Everything fp32 (argmax trajectory must match numpy; threshold is a single
// scalar 5.06 dominated by the argmax output).

constexpr int Bsz   = 4096;
constexpr int AA    = 256;     // alphabet
constexpr int TT    = 128;     // tag dim
constexpr int STEPS = 30;
constexpr int LDP   = 31 * AA; // probabilities row stride (7936)
constexpr long long BH = (long long)Bsz * AA;       // one [B,256] buffer
constexpr long long PROB_N = (long long)Bsz * 31 * AA;

__device__ __forceinline__ float sigf(float x) { return 1.0f / (1.0f + expf(-x)); }

// ---------------------------------------------------------------------------
// init: zero h(parity0, 3 layers) and c(3 layers); write one-hot(START=1)
// into probabilities[:, 0, :].
// ---------------------------------------------------------------------------
__global__ void init_kernel(float* __restrict__ out, float* __restrict__ h0,
                            float* __restrict__ c0) {
    int idx = blockIdx.x * 256 + threadIdx.x;   // < 4096*256
    #pragma unroll
    for (int l = 0; l < 3; l++) {
        h0[(long long)l * BH + idx] = 0.f;
        c0[(long long)l * BH + idx] = 0.f;
    }
    int row = idx >> 8, col = idx & 255;
    out[(long long)row * LDP + col] = (col == 1) ? 1.0f : 0.0f;
}

// ---------------------------------------------------------------------------
// Fused GEMM(+LSTM cell | +sigmoid) kernel.
// Computes G[m, n] = sum_s X_s[m, :] . W_s[n_row, :] over up to 3 input
// segments, for a 64-row x 128-col tile per block.
// LSTM=true : cols are interleaved (j*4+gate) so each thread holds all 4
//             gates of its hidden units; epilogue does the cell update.
//             grid = (64, 8), 32 hidden units per block.
// LSTM=false: identity column mapping; epilogue = sigmoid + bias, float4
//             store into probabilities. grid = (64, 2), 128 cols per block.
// ---------------------------------------------------------------------------
template <bool LSTM>
__global__ __launch_bounds__(256, 2) void gemm_cell(
    const float* __restrict__ x0, int ldx0, int k0, const float* __restrict__ w0, int ldw0,
    const float* __restrict__ x1, int ldx1, int k1, const float* __restrict__ w1, int ldw1,
    const float* __restrict__ x2, int ldx2, int k2, const float* __restrict__ w2, int ldw2,
    const float* __restrict__ b1, const float* __restrict__ b2,
    float* cbuf, float* hout, int ldo)
{
    __shared__ float xs[32][68];    // [k][m], stride 68: b128-aligned reads
    __shared__ float wsh[32][132];  // [k][n], stride 132

    const int tid = threadIdx.x;
    const int tx = tid & 15;        // 16 col-groups
    const int ty = tid >> 4;        // 16 row-groups (4 rows each)
    const int m0 = blockIdx.x * 64;
    const int j0 = blockIdx.y * (LSTM ? 32 : 128);

    float acc[4][8];
    #pragma unroll
    for (int r = 0; r < 4; r++)
        #pragma unroll
        for (int c = 0; c < 8; c++) acc[r][c] = 0.f;

    const float* Xs[3]  = {x0, x1, x2};
    const float* Ws[3]  = {w0, w1, w2};
    const int    ldxs[3] = {ldx0, ldx1, ldx2};
    const int    ldws[3] = {ldw0, ldw1, ldw2};
    const int    Ks[3]   = {k0, k1, k2};

    #pragma unroll
    for (int s = 0; s < 3; s++) {
        const int K = Ks[s];
        if (K == 0) continue;
        const float* X = Xs[s];
        const float* W = Ws[s];
        const int ldx = ldxs[s], ldw = ldws[s];

        for (int kk = 0; kk < K; kk += 32) {
            // stage X tile: 64 rows x 32 k (coalesced 128B per row-chunk)
            #pragma unroll
            for (int i = 0; i < 8; i++) {
                int lin = tid + i * 256;
                int r = lin >> 5, k = lin & 31;
                xs[k][r] = X[(long long)(m0 + r) * ldx + kk + k];
            }
            // stage W tile: 128 n x 32 k
            #pragma unroll
            for (int i = 0; i < 16; i++) {
                int lin = tid + i * 256;
                int n = lin >> 5, k = lin & 31;
                int grow = LSTM ? ((n & 3) * AA + j0 + (n >> 2)) : (j0 + n);
                wsh[k][n] = W[(long long)grow * ldw + kk + k];
            }
            __syncthreads();
            #pragma unroll 8
            for (int k = 0; k < 32; k++) {
                float4 xv = *reinterpret_cast<const float4*>(&xs[k][ty * 4]);
                float4 wa = *reinterpret_cast<const float4*>(&wsh[k][tx * 4]);
                float4 wb = *reinterpret_cast<const float4*>(&wsh[k][64 + tx * 4]);
                float xr[4] = {xv.x, xv.y, xv.z, xv.w};
                float wr[8] = {wa.x, wa.y, wa.z, wa.w, wb.x, wb.y, wb.z, wb.w};
                #pragma unroll
                for (int r = 0; r < 4; r++)
                    #pragma unroll
                    for (int c = 0; c < 8; c++)
                        acc[r][c] += xr[r] * wr[c];
            }
            __syncthreads();
        }
    }

    if (LSTM) {
        // thread cols: half0 -> gates 0..3 of hidden j0+tx; half1 -> j0+16+tx
        #pragma unroll
        for (int r = 0; r < 4; r++) {
            int row = m0 + ty * 4 + r;
            #pragma unroll
            for (int half = 0; half < 2; half++) {
                int j = j0 + tx + half * 16;
                float gi = acc[r][half * 4 + 0] + b1[0 * AA + j] + b2[0 * AA + j];
                float gf = acc[r][half * 4 + 1] + b1[1 * AA + j] + b2[1 * AA + j];
                float gg = acc[r][half * 4 + 2] + b1[2 * AA + j] + b2[2 * AA + j];
                float go = acc[r][half * 4 + 3] + b1[3 * AA + j] + b2[3 * AA + j];
                long long off = (long long)row * AA + j;
                float cn = sigf(gf) * cbuf[off] + sigf(gi) * tanhf(gg);
                cbuf[off] = cn;
                hout[off] = sigf(go) * tanhf(cn);
            }
        }
    } else {
        #pragma unroll
        for (int r = 0; r < 4; r++) {
            int row = m0 + ty * 4 + r;
            #pragma unroll
            for (int half = 0; half < 2; half++) {
                int col = j0 + half * 64 + tx * 4;
                float4 v;
                v.x = sigf(acc[r][half * 4 + 0] + b1[col + 0]);
                v.y = sigf(acc[r][half * 4 + 1] + b1[col + 1]);
                v.z = sigf(acc[r][half * 4 + 2] + b1[col + 2]);
                v.w = sigf(acc[r][half * 4 + 3] + b1[col + 3]);
                *reinterpret_cast<float4*>(&hout[(long long)row * ldo + col]) = v;
            }
        }
    }
}

// ---------------------------------------------------------------------------
// argmax over 256 cols of probabilities[:, t+1, :]; first-max tie rule.
// One wave per row; 4 rows per block.
// ---------------------------------------------------------------------------
__global__ void argmax_kernel(const float* __restrict__ probs,
                              float* __restrict__ outbuf, int t) {
    int w = threadIdx.x >> 6;
    int l = threadIdx.x & 63;
    int row = blockIdx.x * 4 + w;
    const float* p = probs + (long long)row * LDP + (long long)(t + 1) * AA;
    float4 v = *reinterpret_cast<const float4*>(p + l * 4);
    float bv = v.x; int bi = l * 4;
    if (v.y > bv) { bv = v.y; bi = l * 4 + 1; }
    if (v.z > bv) { bv = v.z; bi = l * 4 + 2; }
    if (v.w > bv) { bv = v.w; bi = l * 4 + 3; }
    #pragma unroll
    for (int off = 32; off > 0; off >>= 1) {
        float ov = __shfl_down(bv, off, 64);
        int   oi = __shfl_down(bi, off, 64);
        if (ov > bv || (ov == bv && oi < bi)) { bv = ov; bi = oi; }
    }
    if (l == 0) outbuf[(long long)row * STEPS + t] = (float)bi;
}

// ---------------------------------------------------------------------------
extern "C" void kernel_launch(void* const* d_in, const int* in_sizes, int n_in,
                              void* d_out, int out_size, void* d_ws, size_t ws_size,
                              hipStream_t stream) {
    const float* tags  = (const float*)d_in[2];
    const float* Wih0  = (const float*)d_in[13];  // [1024, 384]
    const float* Whh0  = (const float*)d_in[14];  // [1024, 256]
    const float* bih0  = (const float*)d_in[15];
    const float* bhh0  = (const float*)d_in[16];
    const float* Wih12 = (const float*)d_in[17];  // [2, 1024, 256]
    const float* Whh12 = (const float*)d_in[18];  // [2, 1024, 256]
    const float* bih12 = (const float*)d_in[19];  // [2, 1024]
    const float* bhh12 = (const float*)d_in[20];
    const float* linW  = (const float*)d_in[21];  // [256, 256]
    const float* linb  = (const float*)d_in[22];

    float* out  = (float*)d_out;
    float* wsp  = (float*)d_ws;
    float* hbuf = wsp;                        // [2 parity][3 layer][B*256]
    float* cbuf = wsp + 6 * BH;               // [3 layer][B*256]
    float* outputs = out + PROB_N;

    init_kernel<<<Bsz, 256, 0, stream>>>(out, hbuf, cbuf);

    for (int t = 0; t < STEPS; t++) {
        int p = t & 1, q = 1 - p;
        float* hp = hbuf + (long long)p * 3 * BH;
        float* hq = hbuf + (long long)q * 3 * BH;
        const float* prob = out + (long long)t * AA;   // probabilities[:, t, :]

        // layer 0: gates = [prob,tags] @ Wih0^T + h @ Whh0^T + b
        gemm_cell<true><<<dim3(64, 8), 256, 0, stream>>>(
            prob, LDP, AA, Wih0, AA + TT,
            tags, TT, TT, Wih0 + AA, AA + TT,
            hp + 0 * BH, AA, AA, Whh0, AA,
            bih0, bhh0,
            cbuf + 0 * BH, hq + 0 * BH, AA);
        // layer 1
        gemm_cell<true><<<dim3(64, 8), 256, 0, stream>>>(
            hq + 0 * BH, AA, AA, Wih12, AA,
            nullptr, 0, 0, nullptr, 0,
            hp + 1 * BH, AA, AA, Whh12, AA,
            bih12, bhh12,
            cbuf + 1 * BH, hq + 1 * BH, AA);
        // layer 2
        gemm_cell<true><<<dim3(64, 8), 256, 0, stream>>>(
            hq + 1 * BH, AA, AA, Wih12 + (long long)4 * AA * AA, AA,
            nullptr, 0, 0, nullptr, 0,
            hp + 2 * BH, AA, AA, Whh12 + (long long)4 * AA * AA, AA,
            bih12 + 4 * AA, bhh12 + 4 * AA,
            cbuf + 2 * BH, hq + 2 * BH, AA);
        // lin + sigmoid -> probabilities[:, t+1, :]
        gemm_cell<false><<<dim3(64, 2), 256, 0, stream>>>(
            hq + 2 * BH, AA, AA, linW, AA,
            nullptr, 0, 0, nullptr, 0,
            nullptr, 0, 0, nullptr, 0,
            linb, nullptr,
            nullptr, out + (long long)(t + 1) * AA, LDP);
        // argmax -> outputs[:, t]
        argmax_kernel<<<Bsz / 4, 256, 0, stream>>>(out, outputs, t);
    }
}